// Round 1
// baseline (96.871 us; speedup 1.0000x reference)
//
#include <hip/hip_runtime.h>
#include <hip/hip_bf16.h>

// Problem constants
#define B_    8
#define QLEN  2048
#define D_    1024
#define H_    16
#define KV_   256
#define HD_   64

// ws layout (float offsets):
//   [0, 8192)      Kvec  (B x 1024)
//   [8192, 16384)  Vvec  (B x 1024)
//   [16384, 16392) c2[b] = clip[b,:] @ scale_w[256:]
//   [16392]        sw1   = sum(scale_w[:256])
#define WS_KVEC 0
#define WS_VVEC 8192
#define WS_C2   16384
#define WS_SW1  16392

__device__ inline float wave_sum(float v) {
#pragma unroll
  for (int off = 32; off > 0; off >>= 1) v += __shfl_xor(v, off, 64);
  return v;
}
__device__ inline float wave_max(float v) {
#pragma unroll
  for (int off = 32; off > 0; off >>= 1) v = fmaxf(v, __shfl_xor(v, off, 64));
  return v;
}
__device__ inline float wave_min(float v) {
#pragma unroll
  for (int off = 32; off > 0; off >>= 1) v = fminf(v, __shfl_xor(v, off, 64));
  return v;
}

// Kernel 1: Kvec/Vvec GEMVs + c2 + sw1.
// blocks 0..1023: 4 waves each; wave handles (sel,b, 4 d-rows).
// block 1024: wave 0 computes sw1 and c2[0..7].
__global__ __launch_bounds__(256) void prep_kernel(
    const float* __restrict__ key, const float* __restrict__ value,
    const float* __restrict__ kw, const float* __restrict__ vw,
    const float* __restrict__ clip, const float* __restrict__ scale_w,
    float* __restrict__ ws) {
  const int lane = threadIdx.x & 63;
  const int waveId = threadIdx.x >> 6;

  if (blockIdx.x == 1024) {
    if (waveId != 0) return;
    const float4* sw4 = reinterpret_cast<const float4*>(scale_w);
    float4 a = sw4[lane];                       // covers scale_w[0..255]
    float s = wave_sum(a.x + a.y + a.z + a.w);
    if (lane == 0) ws[WS_SW1] = s;
    float4 w2 = sw4[64 + lane];                 // scale_w[256..511]
    for (int b = 0; b < B_; ++b) {
      const float4* c4 = reinterpret_cast<const float4*>(clip + b * KV_);
      float4 c = c4[lane];
      float p = c.x * w2.x + c.y * w2.y + c.z * w2.z + c.w * w2.w;
      p = wave_sum(p);
      if (lane == 0) ws[WS_C2 + b] = p;
    }
    return;
  }

  const int W = blockIdx.x * 4 + waveId;  // 0..4095
  const int sel = W >> 11;                // 0=K, 1=V
  const int rem = W & 2047;
  const int b = rem >> 8;
  const int g = rem & 255;                // 4-row group
  const float* x = (sel ? value : key) + b * 1024;
  const float* Wt = sel ? vw : kw;
  const float4* x4 = reinterpret_cast<const float4*>(x);
  float4 xs[4];
#pragma unroll
  for (int i = 0; i < 4; ++i) xs[i] = x4[i * 64 + lane];
  float* outv = ws + (sel ? WS_VVEC : WS_KVEC) + b * 1024;
#pragma unroll
  for (int r = 0; r < 4; ++r) {
    const int d = g * 4 + r;
    const float4* w4 = reinterpret_cast<const float4*>(Wt + (size_t)d * 1024);
    float acc = 0.f;
#pragma unroll
    for (int i = 0; i < 4; ++i) {
      float4 w = w4[i * 64 + lane];
      acc += xs[i].x * w.x + xs[i].y * w.y + xs[i].z * w.z + xs[i].w * w.w;
    }
    acc = wave_sum(acc);
    if (lane == 0) outv[d] = acc;
  }
}

// Kernel 2: per (b,h,q) row: L = sw1 * dot(Q,Kvec)/8 + c2[b] + scale_b,
// attn[row, k] = softmax_k(L * clip[b,k]).  One wave owns 16 rows (same b,h).
__global__ __launch_bounds__(256) void attn_kernel(
    const float* __restrict__ query, const float* __restrict__ clip,
    const float* __restrict__ scale_b, const float* __restrict__ ws,
    float* __restrict__ attn) {
  const int lane = threadIdx.x & 63;
  const int waveId = threadIdx.x >> 6;
  const int rowBase = blockIdx.x * 64 + waveId * 16;  // flat (b,h,q)
  const int b = rowBase >> 15;           // 16*2048 = 32768 rows per b
  const int h = (rowBase >> 11) & 15;
  const int q0 = rowBase & 2047;

  const float kv = ws[WS_KVEC + b * 1024 + h * 64 + lane];
  const float4* c4 = reinterpret_cast<const float4*>(clip + b * KV_);
  const float4 cl = c4[lane];
  const float cmax = wave_max(fmaxf(fmaxf(cl.x, cl.y), fmaxf(cl.z, cl.w)));
  const float cmin = wave_min(fminf(fminf(cl.x, cl.y), fminf(cl.z, cl.w)));
  const float sw1 = ws[WS_SW1];
  const float Lc = ws[WS_C2 + b] + scale_b[0];

  const float* qbase = query + ((size_t)(b * QLEN + q0)) * D_ + h * HD_ + lane;
  float qv[16];
#pragma unroll
  for (int r = 0; r < 16; ++r) qv[r] = qbase[(size_t)r * D_];

  float4* a4 = reinterpret_cast<float4*>(attn) + (size_t)rowBase * 64 + lane;
#pragma unroll
  for (int r = 0; r < 16; ++r) {
    const float s = wave_sum(qv[r] * kv);
    const float L = sw1 * (s * 0.125f) + Lc;   // 1/sqrt(64) = 0.125
    const float m = (L >= 0.f) ? L * cmax : L * cmin;
    float4 e;
    e.x = __expf(L * cl.x - m);
    e.y = __expf(L * cl.y - m);
    e.z = __expf(L * cl.z - m);
    e.w = __expf(L * cl.w - m);
    const float den = wave_sum(e.x + e.y + e.z + e.w);
    const float rd = 1.0f / den;
    e.x *= rd; e.y *= rd; e.z *= rd; e.w *= rd;
    a4[(size_t)r * 64] = e;
  }
}

// Kernel 3: out[b,q,:] = Vvec[b,:]  (pure broadcast write, 67 MB)
__global__ __launch_bounds__(256) void out_kernel(const float* __restrict__ ws,
                                                  float* __restrict__ out) {
  const float4* v4 = reinterpret_cast<const float4*>(ws + WS_VVEC);
  float4* o4 = reinterpret_cast<float4*>(out);
  const int idx = blockIdx.x * 256 + threadIdx.x;  // grid: 4096*256 threads
#pragma unroll
  for (int i = 0; i < 4; ++i) {
    const int j = idx + i * 1048576;   // total 4,194,304 float4
    const int b = j >> 19;             // 2048*256 float4 per batch
    const int d4 = j & 255;
    o4[j] = v4[b * 256 + d4];
  }
}

extern "C" void kernel_launch(void* const* d_in, const int* in_sizes, int n_in,
                              void* d_out, int out_size, void* d_ws, size_t ws_size,
                              hipStream_t stream) {
  const float* query   = (const float*)d_in[0];
  const float* key     = (const float*)d_in[1];
  const float* value   = (const float*)d_in[2];
  const float* clip    = (const float*)d_in[3];
  const float* kw      = (const float*)d_in[4];
  const float* vw      = (const float*)d_in[5];
  const float* scale_w = (const float*)d_in[6];
  const float* scale_b = (const float*)d_in[7];
  float* out  = (float*)d_out;
  float* attn = out + (size_t)B_ * QLEN * D_;   // outputs concatenated flat
  float* ws   = (float*)d_ws;

  hipLaunchKernelGGL(prep_kernel, dim3(1025), dim3(256), 0, stream,
                     key, value, kw, vw, clip, scale_w, ws);
  hipLaunchKernelGGL(attn_kernel, dim3(4096), dim3(256), 0, stream,
                     query, clip, scale_b, ws, attn);
  hipLaunchKernelGGL(out_kernel, dim3(4096), dim3(256), 0, stream, ws, out);
}

// Round 3
// 88.085 us; speedup vs baseline: 1.0997x; 1.0997x over previous
//
#include <hip/hip_runtime.h>
#include <hip/hip_bf16.h>

// Problem constants
#define B_    8
#define QLEN  2048
#define D_    1024
#define H_    16
#define KV_   256
#define HD_   64

typedef float fvec4 __attribute__((ext_vector_type(4)));

// ws layout (float offsets):
//   [0, 8192)      Kvec  (B x 1024)
//   [8192, 16384)  Vvec  (B x 1024)
//   [16384, 16392) c2[b] = clip[b,:] @ scale_w[256:]
//   [16392]        sw1   = sum(scale_w[:256])
#define WS_KVEC 0
#define WS_VVEC 8192
#define WS_C2   16384
#define WS_SW1  16392

__device__ inline float wave_sum(float v) {
#pragma unroll
  for (int off = 32; off > 0; off >>= 1) v += __shfl_xor(v, off, 64);
  return v;
}
__device__ inline float wave_max(float v) {
#pragma unroll
  for (int off = 32; off > 0; off >>= 1) v = fmaxf(v, __shfl_xor(v, off, 64));
  return v;
}
__device__ inline float wave_min(float v) {
#pragma unroll
  for (int off = 32; off > 0; off >>= 1) v = fminf(v, __shfl_xor(v, off, 64));
  return v;
}

// Paired reduction: sum p0 and p1 over all 64 lanes simultaneously.
// Returns both sums broadcast to every lane. 7 shuffles for 2 rows.
__device__ inline void pair_sum(float p0, float p1, int lane, float& s0, float& s1) {
  const bool lo = (lane < 32);
  float x = lo ? p1 : p0;
  float t = __shfl_xor(x, 32, 64);
  float c = (lo ? p0 : p1) + t;   // lanes<32: row0 over {l,l+32}; lanes>=32: row1
#pragma unroll
  for (int off = 16; off > 0; off >>= 1) c += __shfl_xor(c, off, 64);
  float u = __shfl_xor(c, 32, 64);
  s0 = lo ? c : u;
  s1 = lo ? u : c;
}

// Kernel 1: Kvec/Vvec GEMVs + c2 + sw1.
__global__ __launch_bounds__(256) void prep_kernel(
    const float* __restrict__ key, const float* __restrict__ value,
    const float* __restrict__ kw, const float* __restrict__ vw,
    const float* __restrict__ clip, const float* __restrict__ scale_w,
    float* __restrict__ ws) {
  const int lane = threadIdx.x & 63;
  const int waveId = threadIdx.x >> 6;

  if (blockIdx.x == 1024) {
    if (waveId != 0) return;
    const float4* sw4 = reinterpret_cast<const float4*>(scale_w);
    float4 a = sw4[lane];                       // scale_w[0..255]
    float s = wave_sum(a.x + a.y + a.z + a.w);
    if (lane == 0) ws[WS_SW1] = s;
    float4 w2 = sw4[64 + lane];                 // scale_w[256..511]
    for (int b = 0; b < B_; ++b) {
      const float4* c4 = reinterpret_cast<const float4*>(clip + b * KV_);
      float4 c = c4[lane];
      float p = c.x * w2.x + c.y * w2.y + c.z * w2.z + c.w * w2.w;
      p = wave_sum(p);
      if (lane == 0) ws[WS_C2 + b] = p;
    }
    return;
  }

  const int W = blockIdx.x * 4 + waveId;  // 0..4095
  const int sel = W >> 11;                // 0=K, 1=V
  const int rem = W & 2047;
  const int b = rem >> 8;
  const int g = rem & 255;                // 4-row group
  const float* x = (sel ? value : key) + b * 1024;
  const float* Wt = sel ? vw : kw;
  const float4* x4 = reinterpret_cast<const float4*>(x);
  float4 xs[4];
#pragma unroll
  for (int i = 0; i < 4; ++i) xs[i] = x4[i * 64 + lane];
  float* outv = ws + (sel ? WS_VVEC : WS_KVEC) + b * 1024;
#pragma unroll
  for (int r = 0; r < 4; ++r) {
    const int d = g * 4 + r;
    const float4* w4 = reinterpret_cast<const float4*>(Wt + (size_t)d * 1024);
    float acc = 0.f;
#pragma unroll
    for (int i = 0; i < 4; ++i) {
      float4 w = w4[i * 64 + lane];
      acc += xs[i].x * w.x + xs[i].y * w.y + xs[i].z * w.z + xs[i].w * w.w;
    }
    acc = wave_sum(acc);
    if (lane == 0) outv[d] = acc;
  }
}

// Kernel 2: per (b,h,q) row: L = sw1 * dot(Q,Kvec)/8 + c2[b] + scale_b,
// attn[row, k] = softmax_k(L * clip[b,k]).  One wave owns 16 rows.
// Fused: also broadcasts out[b,q,:] = Vvec[b,:].
__global__ __launch_bounds__(256) void attn_kernel(
    const float* __restrict__ query, const float* __restrict__ clip,
    const float* __restrict__ scale_b, const float* __restrict__ ws,
    float* __restrict__ attn, float* __restrict__ out) {
  const int lane = threadIdx.x & 63;
  const int waveId = threadIdx.x >> 6;
  const int rowBase = blockIdx.x * 64 + waveId * 16;  // flat (b,h,q)
  const int b = rowBase >> 15;           // 16*2048 = 32768 rows per b
  const int h = (rowBase >> 11) & 15;
  const int q0 = rowBase & 2047;

  const float kv = ws[WS_KVEC + b * 1024 + h * 64 + lane];
  const float4* c4 = reinterpret_cast<const float4*>(clip + b * KV_);
  const float4 cl = c4[lane];
  const float cmax = wave_max(fmaxf(fmaxf(cl.x, cl.y), fmaxf(cl.z, cl.w)));
  const float cmin = wave_min(fminf(fminf(cl.x, cl.y), fminf(cl.z, cl.w)));
  const float sw1 = ws[WS_SW1];
  const float Lc = ws[WS_C2 + b] + scale_b[0];

  const float* qbase = query + ((size_t)(b * QLEN + q0)) * D_ + h * HD_ + lane;
  float qv[16];
#pragma unroll
  for (int r = 0; r < 16; ++r) qv[r] = __builtin_nontemporal_load(&qbase[(size_t)r * D_]);

  fvec4* a4 = reinterpret_cast<fvec4*>(attn) + (size_t)rowBase * 64 + lane;
#pragma unroll
  for (int r = 0; r < 16; r += 2) {
    float s0, s1;
    pair_sum(qv[r] * kv, qv[r + 1] * kv, lane, s0, s1);
    const float L0 = sw1 * (s0 * 0.125f) + Lc;   // 1/sqrt(64) = 0.125
    const float L1 = sw1 * (s1 * 0.125f) + Lc;
    const float m0 = (L0 >= 0.f) ? L0 * cmax : L0 * cmin;
    const float m1 = (L1 >= 0.f) ? L1 * cmax : L1 * cmin;
    fvec4 e0, e1;
    e0.x = __expf(L0 * cl.x - m0); e0.y = __expf(L0 * cl.y - m0);
    e0.z = __expf(L0 * cl.z - m0); e0.w = __expf(L0 * cl.w - m0);
    e1.x = __expf(L1 * cl.x - m1); e1.y = __expf(L1 * cl.y - m1);
    e1.z = __expf(L1 * cl.z - m1); e1.w = __expf(L1 * cl.w - m1);
    float den0, den1;
    pair_sum(e0.x + e0.y + e0.z + e0.w, e1.x + e1.y + e1.z + e1.w, lane, den0, den1);
    const float rd0 = 1.0f / den0;
    const float rd1 = 1.0f / den1;
    e0 *= rd0;
    e1 *= rd1;
    __builtin_nontemporal_store(e0, &a4[(size_t)r * 64]);
    __builtin_nontemporal_store(e1, &a4[(size_t)(r + 1) * 64]);
  }

  // Fused out-broadcast: out[b,q,:] = Vvec[b,:]. 4,194,304 float4 total,
  // 1024 per block (grid is 4096 blocks).
  {
    const fvec4* v4 = reinterpret_cast<const fvec4*>(ws + WS_VVEC);
    fvec4* o4 = reinterpret_cast<fvec4*>(out);
    const int idx = blockIdx.x * 256 + threadIdx.x;
#pragma unroll
    for (int i = 0; i < 4; ++i) {
      const int j = idx + i * 1048576;   // 2048*256 float4 per batch
      const int ob = j >> 19;
      const int d4 = j & 255;
      fvec4 v = v4[ob * 256 + d4];
      __builtin_nontemporal_store(v, &o4[j]);
    }
  }
}

extern "C" void kernel_launch(void* const* d_in, const int* in_sizes, int n_in,
                              void* d_out, int out_size, void* d_ws, size_t ws_size,
                              hipStream_t stream) {
  const float* query   = (const float*)d_in[0];
  const float* key     = (const float*)d_in[1];
  const float* value   = (const float*)d_in[2];
  const float* clip    = (const float*)d_in[3];
  const float* kw      = (const float*)d_in[4];
  const float* vw      = (const float*)d_in[5];
  const float* scale_w = (const float*)d_in[6];
  const float* scale_b = (const float*)d_in[7];
  float* out  = (float*)d_out;
  float* attn = out + (size_t)B_ * QLEN * D_;   // outputs concatenated flat
  float* ws   = (float*)d_ws;

  hipLaunchKernelGGL(prep_kernel, dim3(1025), dim3(256), 0, stream,
                     key, value, kw, vw, clip, scale_w, ws);
  hipLaunchKernelGGL(attn_kernel, dim3(4096), dim3(256), 0, stream,
                     query, clip, scale_b, ws, attn, out);
}

// Round 4
// 87.483 us; speedup vs baseline: 1.1073x; 1.0069x over previous
//
#include <hip/hip_runtime.h>
#include <hip/hip_bf16.h>

// Problem constants
#define B_    8
#define QLEN  2048
#define D_    1024
#define H_    16
#define KV_   256
#define HD_   64

typedef float fvec4 __attribute__((ext_vector_type(4)));

// ws layout (float offsets):
#define WS_KVEC 0
#define WS_VVEC 8192
#define WS_C2   16384
#define WS_SW1  16392

__device__ inline float wave_sum(float v) {
#pragma unroll
  for (int off = 32; off > 0; off >>= 1) v += __shfl_xor(v, off, 64);
  return v;
}
__device__ inline float wave_max(float v) {
#pragma unroll
  for (int off = 32; off > 0; off >>= 1) v = fmaxf(v, __shfl_xor(v, off, 64));
  return v;
}
__device__ inline float wave_min(float v) {
#pragma unroll
  for (int off = 32; off > 0; off >>= 1) v = fminf(v, __shfl_xor(v, off, 64));
  return v;
}

// N independent full-wave butterfly sums: 6 dependent levels total,
// N-way ILP inside each level (vs N serial 6-deep chains).
template <int N>
__device__ inline void multi_sum(float* v) {
#pragma unroll
  for (int off = 32; off > 0; off >>= 1) {
#pragma unroll
    for (int r = 0; r < N; ++r) v[r] += __shfl_xor(v[r], off, 64);
  }
}

// Kernel 1: Kvec/Vvec GEMVs + c2 + sw1.
__global__ __launch_bounds__(256) void prep_kernel(
    const float* __restrict__ key, const float* __restrict__ value,
    const float* __restrict__ kw, const float* __restrict__ vw,
    const float* __restrict__ clip, const float* __restrict__ scale_w,
    float* __restrict__ ws) {
  const int lane = threadIdx.x & 63;
  const int waveId = threadIdx.x >> 6;

  if (blockIdx.x == 1024) {
    if (waveId != 0) return;
    const float4* sw4 = reinterpret_cast<const float4*>(scale_w);
    float4 a = sw4[lane];                       // scale_w[0..255]
    float s = wave_sum(a.x + a.y + a.z + a.w);
    if (lane == 0) ws[WS_SW1] = s;
    float4 w2 = sw4[64 + lane];                 // scale_w[256..511]
    for (int b = 0; b < B_; ++b) {
      const float4* c4 = reinterpret_cast<const float4*>(clip + b * KV_);
      float4 c = c4[lane];
      float p = c.x * w2.x + c.y * w2.y + c.z * w2.z + c.w * w2.w;
      p = wave_sum(p);
      if (lane == 0) ws[WS_C2 + b] = p;
    }
    return;
  }

  const int W = blockIdx.x * 4 + waveId;  // 0..4095
  const int sel = W >> 11;                // 0=K, 1=V
  const int rem = W & 2047;
  const int b = rem >> 8;
  const int g = rem & 255;                // 4-row group
  const float* x = (sel ? value : key) + b * 1024;
  const float* Wt = sel ? vw : kw;
  const float4* x4 = reinterpret_cast<const float4*>(x);
  float4 xs[4];
#pragma unroll
  for (int i = 0; i < 4; ++i) xs[i] = x4[i * 64 + lane];
  float* outv = ws + (sel ? WS_VVEC : WS_KVEC) + b * 1024;
  float acc[4];
#pragma unroll
  for (int r = 0; r < 4; ++r) {
    const int d = g * 4 + r;
    const float4* w4 = reinterpret_cast<const float4*>(Wt + (size_t)d * 1024);
    acc[r] = 0.f;
#pragma unroll
    for (int i = 0; i < 4; ++i) {
      float4 w = w4[i * 64 + lane];
      acc[r] += xs[i].x * w.x + xs[i].y * w.y + xs[i].z * w.z + xs[i].w * w.w;
    }
  }
  multi_sum<4>(acc);
  if (lane < 4) outv[g * 4 + lane] = acc[lane];
}

// Kernel 2: per (b,h,q) row: L = sw1 * dot(Q,Kvec)/8 + c2[b] + scale_b,
// attn[row, k] = softmax_k(L * clip[b,k]); out[b,q,:] = Vvec[b,:].
// One wave owns 16 rows; all reductions are 16-row-parallel butterflies.
__global__ __launch_bounds__(256) void attn_kernel(
    const float* __restrict__ query, const float* __restrict__ clip,
    const float* __restrict__ scale_b, const float* __restrict__ ws,
    float* __restrict__ attn, float* __restrict__ out) {
  const int lane = threadIdx.x & 63;
  const int waveId = threadIdx.x >> 6;
  const int rowBase = blockIdx.x * 64 + waveId * 16;  // flat (b,h,q)
  const int b = rowBase >> 15;           // 16*2048 = 32768 rows per b
  const int h = (rowBase >> 11) & 15;
  const int q0 = rowBase & 2047;

  // Out-broadcast first: stores start flowing before the compute phase.
  {
    const fvec4* v4 = reinterpret_cast<const fvec4*>(ws + WS_VVEC);
    fvec4* o4 = reinterpret_cast<fvec4*>(out);
    const int idx = blockIdx.x * 256 + threadIdx.x;
#pragma unroll
    for (int i = 0; i < 4; ++i) {
      const int j = idx + i * 1048576;   // 2048*256 float4 per batch
      const int ob = j >> 19;
      const int d4 = j & 255;
      fvec4 v = v4[ob * 256 + d4];
      __builtin_nontemporal_store(v, &o4[j]);
    }
  }

  const float kv = ws[WS_KVEC + b * 1024 + h * 64 + lane];
  const float4* c4 = reinterpret_cast<const float4*>(clip + b * KV_);
  const float4 cl = c4[lane];
  const float cmax = wave_max(fmaxf(fmaxf(cl.x, cl.y), fmaxf(cl.z, cl.w)));
  const float cmin = wave_min(fminf(fminf(cl.x, cl.y), fminf(cl.z, cl.w)));
  const float sw1 = ws[WS_SW1];
  const float Lc = ws[WS_C2 + b] + scale_b[0];

  const float* qbase = query + ((size_t)(b * QLEN + q0)) * D_ + h * HD_ + lane;
  float qv[16];
#pragma unroll
  for (int r = 0; r < 16; ++r) qv[r] = __builtin_nontemporal_load(&qbase[(size_t)r * D_]);

  // Phase 1: all 16 dot-products, 6 dependent shuffle levels total.
  float sp[16];
#pragma unroll
  for (int r = 0; r < 16; ++r) sp[r] = qv[r] * kv;
  multi_sum<16>(sp);

  float L[16], m[16];
#pragma unroll
  for (int r = 0; r < 16; ++r) {
    L[r] = sw1 * (sp[r] * 0.125f) + Lc;   // 1/sqrt(64) = 0.125
    m[r] = (L[r] >= 0.f) ? L[r] * cmax : L[r] * cmin;
  }

  // Phase 2: all 16 softmax denominators, 6 dependent shuffle levels.
  float dp[16];
#pragma unroll
  for (int r = 0; r < 16; ++r) {
    dp[r] = __expf(L[r] * cl.x - m[r]) + __expf(L[r] * cl.y - m[r]) +
            __expf(L[r] * cl.z - m[r]) + __expf(L[r] * cl.w - m[r]);
  }
  multi_sum<16>(dp);

  // Phase 3: recompute exps, normalize, store (1 KB coalesced per row).
  fvec4* a4 = reinterpret_cast<fvec4*>(attn) + (size_t)rowBase * 64 + lane;
#pragma unroll
  for (int r = 0; r < 16; ++r) {
    const float rd = 1.0f / dp[r];
    fvec4 e;
    e.x = __expf(L[r] * cl.x - m[r]) * rd;
    e.y = __expf(L[r] * cl.y - m[r]) * rd;
    e.z = __expf(L[r] * cl.z - m[r]) * rd;
    e.w = __expf(L[r] * cl.w - m[r]) * rd;
    __builtin_nontemporal_store(e, &a4[(size_t)r * 64]);
  }
}

extern "C" void kernel_launch(void* const* d_in, const int* in_sizes, int n_in,
                              void* d_out, int out_size, void* d_ws, size_t ws_size,
                              hipStream_t stream) {
  const float* query   = (const float*)d_in[0];
  const float* key     = (const float*)d_in[1];
  const float* value   = (const float*)d_in[2];
  const float* clip    = (const float*)d_in[3];
  const float* kw      = (const float*)d_in[4];
  const float* vw      = (const float*)d_in[5];
  const float* scale_w = (const float*)d_in[6];
  const float* scale_b = (const float*)d_in[7];
  float* out  = (float*)d_out;
  float* attn = out + (size_t)B_ * QLEN * D_;   // outputs concatenated flat
  float* ws   = (float*)d_ws;

  hipLaunchKernelGGL(prep_kernel, dim3(1025), dim3(256), 0, stream,
                     key, value, kw, vw, clip, scale_w, ws);
  hipLaunchKernelGGL(attn_kernel, dim3(4096), dim3(256), 0, stream,
                     query, clip, scale_b, ws, attn, out);
}

// Round 5
// 82.931 us; speedup vs baseline: 1.1681x; 1.0549x over previous
//
#include <hip/hip_runtime.h>
#include <hip/hip_bf16.h>

// Problem constants
#define B_    8
#define QLEN  2048
#define D_    1024
#define H_    16
#define KV_   256
#define HD_   64

typedef float fvec4 __attribute__((ext_vector_type(4)));

// ws layout (float offsets):
#define WS_KVEC 0        // B x 1024
#define WS_VVEC 8192     // B x 1024
#define WS_C2   16384    // B
#define WS_SW1  16392    // 1
#define WS_L    16400    // 256K floats: L[b,h,q]

__device__ inline float wave_sum(float v) {
#pragma unroll
  for (int off = 32; off > 0; off >>= 1) v += __shfl_xor(v, off, 64);
  return v;
}
__device__ inline float wave_max(float v) {
#pragma unroll
  for (int off = 32; off > 0; off >>= 1) v = fmaxf(v, __shfl_xor(v, off, 64));
  return v;
}
__device__ inline float wave_min(float v) {
#pragma unroll
  for (int off = 32; off > 0; off >>= 1) v = fminf(v, __shfl_xor(v, off, 64));
  return v;
}
template <int N>
__device__ inline void multi_sum(float* v) {
#pragma unroll
  for (int off = 32; off > 0; off >>= 1) {
#pragma unroll
    for (int r = 0; r < N; ++r) v[r] += __shfl_xor(v[r], off, 64);
  }
}

// Kernel 1: Kvec/Vvec GEMVs + c2 + sw1.
__global__ __launch_bounds__(256) void prep_kernel(
    const float* __restrict__ key, const float* __restrict__ value,
    const float* __restrict__ kw, const float* __restrict__ vw,
    const float* __restrict__ clip, const float* __restrict__ scale_w,
    float* __restrict__ ws) {
  const int lane = threadIdx.x & 63;
  const int waveId = threadIdx.x >> 6;

  if (blockIdx.x == 1024) {
    if (waveId != 0) return;
    const float4* sw4 = reinterpret_cast<const float4*>(scale_w);
    float4 a = sw4[lane];                       // scale_w[0..255]
    float s = wave_sum(a.x + a.y + a.z + a.w);
    if (lane == 0) ws[WS_SW1] = s;
    float4 w2 = sw4[64 + lane];                 // scale_w[256..511]
    for (int b = 0; b < B_; ++b) {
      const float4* c4 = reinterpret_cast<const float4*>(clip + b * KV_);
      float4 c = c4[lane];
      float p = c.x * w2.x + c.y * w2.y + c.z * w2.z + c.w * w2.w;
      p = wave_sum(p);
      if (lane == 0) ws[WS_C2 + b] = p;
    }
    return;
  }

  const int W = blockIdx.x * 4 + waveId;  // 0..4095
  const int sel = W >> 11;                // 0=K, 1=V
  const int rem = W & 2047;
  const int b = rem >> 8;
  const int g = rem & 255;                // 4-row group
  const float* x = (sel ? value : key) + b * 1024;
  const float* Wt = sel ? vw : kw;
  const float4* x4 = reinterpret_cast<const float4*>(x);
  float4 xs[4];
#pragma unroll
  for (int i = 0; i < 4; ++i) xs[i] = x4[i * 64 + lane];
  float* outv = ws + (sel ? WS_VVEC : WS_KVEC) + b * 1024;
  float acc[4];
#pragma unroll
  for (int r = 0; r < 4; ++r) {
    const int d = g * 4 + r;
    const float4* w4 = reinterpret_cast<const float4*>(Wt + (size_t)d * 1024);
    acc[r] = 0.f;
#pragma unroll
    for (int i = 0; i < 4; ++i) {
      float4 w = w4[i * 64 + lane];
      acc[r] += xs[i].x * w.x + xs[i].y * w.y + xs[i].z * w.z + xs[i].w * w.w;
    }
  }
  multi_sum<4>(acc);
  if (lane < 4) outv[g * 4 + lane] = acc[lane];
}

// Kernel 2: L[row] = sw1 * dot(Q_row, Kvec_head)/8 + c2[b] + scale_b.
// Wave owns 16 rows; float4 Q loads; 16-lane group reductions.
__global__ __launch_bounds__(256) void qdot_kernel(
    const float* __restrict__ query, const float* __restrict__ scale_b,
    float* __restrict__ ws) {
  const int lane = threadIdx.x & 63;
  const int waveId = threadIdx.x >> 6;
  const int rowBase = blockIdx.x * 64 + waveId * 16;  // flat (b,h,q)
  const int b = rowBase >> 15;
  const int h = (rowBase >> 11) & 15;
  const int q0 = rowBase & 2047;
  const int g = lane >> 4;   // row sub-group 0..3
  const int c = lane & 15;   // float4 column within 64-dim head slice

  const fvec4 kvv = reinterpret_cast<const fvec4*>(ws + WS_KVEC + b * 1024 + h * HD_)[c];
  const float sw1 = ws[WS_SW1];
  const float Lc = ws[WS_C2 + b] + scale_b[0];

  const float* qb = query + ((size_t)(b * QLEN + q0)) * D_ + h * HD_;
  float p[4];
#pragma unroll
  for (int j = 0; j < 4; ++j) {
    const fvec4 q4 = __builtin_nontemporal_load(
        reinterpret_cast<const fvec4*>(qb + (size_t)(j * 4 + g) * D_) + c);
    p[j] = q4.x * kvv.x + q4.y * kvv.y + q4.z * kvv.z + q4.w * kvv.w;
  }
  // reduce within each aligned 16-lane group (4 independent rows at a time)
#pragma unroll
  for (int off = 1; off <= 8; off <<= 1) {
#pragma unroll
    for (int j = 0; j < 4; ++j) p[j] += __shfl_xor(p[j], off, 64);
  }
  // lane l = g*16 + j (j = c < 4) holds row j*4+g sum in p[j]
  if (c < 4) {
    const float sp = (c == 0) ? p[0] : (c == 1) ? p[1] : (c == 2) ? p[2] : p[3];
    ws[WS_L + rowBase + c * 4 + g] = sw1 * (sp * 0.125f) + Lc;
  }
}

// Kernel 3: pure streaming. attn[row,:] = softmax(L[row]*cl)/den; out = Vvec bcast.
// Wave owns 32 contiguous rows (all same b) + 8 out-chunks of 1KB.
__global__ __launch_bounds__(256) void stream_kernel(
    const float* __restrict__ clip, const float* __restrict__ ws,
    float* __restrict__ attn, float* __restrict__ out) {
  const int lane = threadIdx.x & 63;
  const int gwave = (blockIdx.x * 256 + threadIdx.x) >> 6;  // 0..8191
  const int row0 = gwave * 32;
  const int b = row0 >> 15;   // 32768 rows per batch; 32 | 32768 so b uniform

  const fvec4 cl = reinterpret_cast<const fvec4*>(clip + b * KV_)[lane];
  const float cmax = wave_max(fmaxf(fmaxf(cl.x, cl.y), fmaxf(cl.z, cl.w)));
  const float cmin = wave_min(fminf(fminf(cl.x, cl.y), fminf(cl.z, cl.w)));
  const float* Lp = ws + WS_L + row0;

  fvec4* a4 = reinterpret_cast<fvec4*>(attn) + (size_t)row0 * 64 + lane;
#pragma unroll 4
  for (int i = 0; i < 32; ++i) {
    const float Ld = Lp[i];
    const float m = (Ld >= 0.f) ? Ld * cmax : Ld * cmin;
    fvec4 e;
    e.x = __expf(Ld * cl.x - m);
    e.y = __expf(Ld * cl.y - m);
    e.z = __expf(Ld * cl.z - m);
    e.w = __expf(Ld * cl.w - m);
    const float den = wave_sum(e.x + e.y + e.z + e.w);
    e *= (1.0f / den);
    __builtin_nontemporal_store(e, &a4[(size_t)i * 64]);
  }

  // out broadcast: 65536 chunks of 1KB; this wave does 8.
  const fvec4* v4 = reinterpret_cast<const fvec4*>(ws + WS_VVEC);
  fvec4* o4 = reinterpret_cast<fvec4*>(out);
#pragma unroll
  for (int i = 0; i < 8; ++i) {
    const int j = (gwave * 8 + i) * 64 + lane;  // float4 index
    const int ob = j >> 19;                     // 2048*256 float4 per batch
    const int d4 = j & 255;
    fvec4 v = v4[ob * 256 + d4];
    __builtin_nontemporal_store(v, &o4[j]);
  }
}

extern "C" void kernel_launch(void* const* d_in, const int* in_sizes, int n_in,
                              void* d_out, int out_size, void* d_ws, size_t ws_size,
                              hipStream_t stream) {
  const float* query   = (const float*)d_in[0];
  const float* key     = (const float*)d_in[1];
  const float* value   = (const float*)d_in[2];
  const float* clip    = (const float*)d_in[3];
  const float* kw      = (const float*)d_in[4];
  const float* vw      = (const float*)d_in[5];
  const float* scale_w = (const float*)d_in[6];
  const float* scale_b = (const float*)d_in[7];
  float* out  = (float*)d_out;
  float* attn = out + (size_t)B_ * QLEN * D_;   // outputs concatenated flat
  float* ws   = (float*)d_ws;

  hipLaunchKernelGGL(prep_kernel, dim3(1025), dim3(256), 0, stream,
                     key, value, kw, vw, clip, scale_w, ws);
  hipLaunchKernelGGL(qdot_kernel, dim3(4096), dim3(256), 0, stream,
                     query, scale_b, ws);
  hipLaunchKernelGGL(stream_kernel, dim3(2048), dim3(256), 0, stream,
                     clip, ws, attn, out);
}